// Round 12
// baseline (1773.564 us; speedup 1.0000x reference)
//
#include <hip/hip_runtime.h>

typedef _Float16 half8 __attribute__((ext_vector_type(8)));
typedef _Float16 half4v __attribute__((ext_vector_type(4)));
typedef float f32x4 __attribute__((ext_vector_type(4)));

#define OFF_PRED 26214400      // 32*128*128*50
#define OFF_XU   56934400      // OFF_PRED + 32*64*300*50

// ---- K0: build M in MFMA-fragment order.
// Logical M[640][320]: rows 0..255 = C, 256..555 = A, rest 0; cols k<300 real, else 0.
// dst elem = ((mt*10 + ks)*64 + lane)*8 + e, m = mt*16 + (lane&15), k = ks*32 + (lane>>4)*8 + e.
__global__ void build_M(const float* __restrict__ A, const float* __restrict__ C,
                        _Float16* __restrict__ M) {
    int idx = blockIdx.x * 256 + threadIdx.x;
    if (idx >= 640 * 320) return;
    int e    = idx & 7;
    int lane = (idx >> 3) & 63;
    int fs   = idx >> 9;                        // mt*10 + ks
    int mt = fs / 10, ks = fs % 10;
    int m = mt * 16 + (lane & 15);
    int k = ks * 32 + (lane >> 4) * 8 + e;
    float v = 0.f;
    if (k < 300) {
        if (m < 256) v = C[m * 300 + k];
        else if (m < 556) v = A[(m - 256) * 300 + k];
    }
    M[idx] = (_Float16)v;
}

// ---- DIAGNOSTIC PROBE: the K-loop compute phase (M L2-loads + LDS A-frags + MFMA)
//      in R10's exact block config, repeated 8x. No stage, no epilogue. acc kept
//      live via asm (rule #17) so nothing is DCE'd. Appears in rocprof as its own
//      dispatch: dur/8 = one compute-phase cost.
__global__ __launch_bounds__(256, 3) void probe_comp(const _Float16* __restrict__ M) {
    __shared__ _Float16 lds[64 * 320];
    char* ldsb = (char*)lds;
    const int tid = threadIdx.x;
    const int wave = tid >> 6, lane = tid & 63;
    const int lr = lane & 15, lg = lane >> 4;
    const int mhalf = blockIdx.x & 1;

    #pragma unroll
    for (int u = 0; u < 20; u++)
        *(unsigned long long*)(ldsb + tid * 8 + u * 2048) = 0ULL;
    __syncthreads();

    f32x4 acc[5][4];
    #pragma unroll
    for (int j = 0; j < 5; j++)
        #pragma unroll
        for (int nt = 0; nt < 4; nt++)
            acc[j][nt] = (f32x4){0.f, 0.f, 0.f, 0.f};

    const _Float16* Mw = M + (mhalf * 4 + wave) * 50 * 512 + lane * 8;
    #define LDSA(nt, ks) (*(const half8*)(ldsb + ((nt) * 16 + lr) * 640 + \
                         (((ks) * 64 + lg * 16) ^ ((lr & 7) << 4))))

    #pragma unroll 1
    for (int rep = 0; rep < 8; ++rep) {
        #pragma unroll
        for (int ks = 0; ks < 10; ks++) {
            half8 bf0 = *(const half8*)(Mw + (0 * 10 + ks) * 512);
            half8 bf1 = *(const half8*)(Mw + (1 * 10 + ks) * 512);
            half8 bf2 = *(const half8*)(Mw + (2 * 10 + ks) * 512);
            half8 bf3 = *(const half8*)(Mw + (3 * 10 + ks) * 512);
            half8 bf4 = *(const half8*)(Mw + (4 * 10 + ks) * 512);
            #pragma unroll
            for (int nt = 0; nt < 4; nt++) {
                half8 a = LDSA(nt, ks);
                acc[0][nt] = __builtin_amdgcn_mfma_f32_16x16x32_f16(a, bf0, acc[0][nt], 0, 0, 0);
                acc[1][nt] = __builtin_amdgcn_mfma_f32_16x16x32_f16(a, bf1, acc[1][nt], 0, 0, 0);
                acc[2][nt] = __builtin_amdgcn_mfma_f32_16x16x32_f16(a, bf2, acc[2][nt], 0, 0, 0);
                acc[3][nt] = __builtin_amdgcn_mfma_f32_16x16x32_f16(a, bf3, acc[3][nt], 0, 0, 0);
                acc[4][nt] = __builtin_amdgcn_mfma_f32_16x16x32_f16(a, bf4, acc[4][nt], 0, 0, 0);
            }
        }
    }
    #undef LDSA

    #pragma unroll
    for (int j = 0; j < 5; j++)
        #pragma unroll
        for (int nt = 0; nt < 4; nt++)
            asm volatile("" :: "v"(acc[j][nt]));
}

// ---- K1: block (bp, mhalf) — UNCHANGED from R10 (best verified structure).
__global__ __launch_bounds__(256, 3) void gemm_main(
    const float* __restrict__ X, const float* __restrict__ x0,
    const _Float16* __restrict__ M, float* __restrict__ out)
{
    __shared__ _Float16 lds[64 * 320];   // 40960 B
    char* ldsb = (char*)lds;
    const int bid = blockIdx.x;
    const int bp = bid >> 1, mhalf = bid & 1;
    const int b = bp >> 6, p = bp & 63;
    const int tid = threadIdx.x;
    const float* Xbp = X + bp * 15000;

    const int wave = tid >> 6, lane = tid & 63;
    const int lr = lane & 15, lg = lane >> 4;
    const int g = wave;

    #pragma unroll
    for (int u = 0; u < 20; u++)
        *(unsigned long long*)(ldsb + tid * 8 + u * 2048) = 0ULL;
    __syncthreads();

    if (tid < 75) {
        f32x4 v = *(const f32x4*)(x0 + bp * 300 + tid * 4);
        half4v h4 = { (_Float16)v.x, (_Float16)v.y, (_Float16)v.z, (_Float16)v.w };
        *(half4v*)(ldsb + tid * 8) = h4;
    }
    for (int i = tid; i < 3750; i += 256) {
        int t = i % 50, jq = i / 50;
        const float* s = Xbp + (jq * 4) * 50 + t;
        half4v h4 = { (_Float16)s[0], (_Float16)s[50], (_Float16)s[100], (_Float16)s[150] };
        int row = t + 1;
        *(half4v*)(ldsb + row * 640 + ((jq * 8) ^ ((row & 7) << 4))) = h4;
    }
    __syncthreads();

    f32x4 acc[5][4];
    #pragma unroll
    for (int j = 0; j < 5; j++)
        #pragma unroll
        for (int nt = 0; nt < 4; nt++)
            acc[j][nt] = (f32x4){0.f, 0.f, 0.f, 0.f};

    const _Float16* Mw = M + (mhalf * 4 + g) * 50 * 512 + lane * 8;
    #define LDSA(nt, ks) (*(const half8*)(ldsb + ((nt) * 16 + lr) * 640 + \
                         (((ks) * 64 + lg * 16) ^ ((lr & 7) << 4))))

    #pragma unroll
    for (int ks = 0; ks < 10; ks++) {
        half8 bf0 = *(const half8*)(Mw + (0 * 10 + ks) * 512);
        half8 bf1 = *(const half8*)(Mw + (1 * 10 + ks) * 512);
        half8 bf2 = *(const half8*)(Mw + (2 * 10 + ks) * 512);
        half8 bf3 = *(const half8*)(Mw + (3 * 10 + ks) * 512);
        half8 bf4 = *(const half8*)(Mw + (4 * 10 + ks) * 512);
        #pragma unroll
        for (int nt = 0; nt < 4; nt++) {
            half8 a = LDSA(nt, ks);
            acc[0][nt] = __builtin_amdgcn_mfma_f32_16x16x32_f16(a, bf0, acc[0][nt], 0, 0, 0);
            acc[1][nt] = __builtin_amdgcn_mfma_f32_16x16x32_f16(a, bf1, acc[1][nt], 0, 0, 0);
            acc[2][nt] = __builtin_amdgcn_mfma_f32_16x16x32_f16(a, bf2, acc[2][nt], 0, 0, 0);
            acc[3][nt] = __builtin_amdgcn_mfma_f32_16x16x32_f16(a, bf3, acc[3][nt], 0, 0, 0);
            acc[4][nt] = __builtin_amdgcn_mfma_f32_16x16x32_f16(a, bf4, acc[4][nt], 0, 0, 0);
        }
    }

    const int gr = p >> 3, gc = p & 7;
    #pragma unroll
    for (int j = 0; j < 5; j++) {
        int colm = mhalf * 320 + g * 80 + j * 16 + lr;
        if (colm < 256) {
            int base = b * 819200 + ((gr * 16 + (colm >> 4)) * 128 + gc * 16 + (colm & 15)) * 50;
            #pragma unroll
            for (int nt = 0; nt < 4; nt++) {
                int t0 = nt * 16 + lg * 4;
                if (t0 == 0) {
                    out[base + 0] = acc[j][0][1];
                    out[base + 1] = acc[j][0][2];
                    out[base + 2] = acc[j][0][3];
                } else if (t0 <= 46) {
                    f32x4 v = acc[j][nt];
                    __builtin_memcpy(&out[base + t0 - 1], &v, 16);
                } else if (t0 == 48) {
                    out[base + 47] = acc[j][nt][0];
                    out[base + 48] = acc[j][nt][1];
                    out[base + 49] = acc[j][nt][2];
                }
            }
        } else if (colm < 556) {
            int base = OFF_PRED + (bp * 300 + (colm - 256)) * 50;
            #pragma unroll
            for (int nt = 0; nt < 4; nt++) {
                int t0 = nt * 16 + lg * 4;
                if (t0 <= 46) {
                    f32x4 v = acc[j][nt];
                    __builtin_memcpy(&out[base + t0], &v, 16);
                } else if (t0 == 48) {
                    out[base + 48] = acc[j][nt][0];
                    out[base + 49] = acc[j][nt][1];
                }
            }
        }
    }
    #undef LDSA
}

// ---- K2: X_U[b,i,t] = 0.5*(1+exp(-(B·U)[b,i,t])) * sum_p |X[b,p,i,t]|
__global__ void xu_kernel(const float* __restrict__ X, const float* __restrict__ U,
                          const float* __restrict__ B, float* __restrict__ out) {
    int id = blockIdx.x * 256 + threadIdx.x;
    if (id >= 480000) return;
    int t = id % 50;
    int i = (id / 50) % 300;
    int b = id / 15000;
    const float* xp = X + b * 960000 + i * 50 + t;
    float s = 0.f;
    #pragma unroll 8
    for (int pp = 0; pp < 64; pp++) s += fabsf(xp[pp * 15000]);
    float bu = 0.f;
    const float* up = U + b * 2000 + t;
    const float* Bp = B + i * 40;
    #pragma unroll 8
    for (int q = 0; q < 40; q++) bu += Bp[q] * up[q * 50];
    out[OFF_XU + id] = 0.5f * (1.f + expf(-bu)) * s;
}

extern "C" void kernel_launch(void* const* d_in, const int* in_sizes, int n_in,
                              void* d_out, int out_size, void* d_ws, size_t ws_size,
                              hipStream_t stream) {
    const float* X  = (const float*)d_in[0];
    const float* U  = (const float*)d_in[1];
    const float* x0 = (const float*)d_in[2];
    const float* A  = (const float*)d_in[3];
    const float* B  = (const float*)d_in[4];
    const float* C  = (const float*)d_in[5];
    float* out = (float*)d_out;
    _Float16* M = (_Float16*)d_ws;      // 640*320*2 = 409,600 B (fragment-ordered)

    build_M<<<800, 256, 0, stream>>>(A, C, M);
    probe_comp<<<4096, 256, 0, stream>>>(M);          // diagnostic: 8x compute phase
    gemm_main<<<4096, 256, 0, stream>>>(X, x0, M, out);
    xu_kernel<<<1875, 256, 0, stream>>>(X, U, B, out);
}

// Round 13
// 139.829 us; speedup vs baseline: 12.6839x; 12.6839x over previous
//
#include <hip/hip_runtime.h>

typedef _Float16 half8 __attribute__((ext_vector_type(8)));
typedef _Float16 half4v __attribute__((ext_vector_type(4)));
typedef float f32x4 __attribute__((ext_vector_type(4)));
typedef unsigned long long ull;

#define OFF_PRED 26214400      // 32*128*128*50
#define OFF_XU   56934400      // OFF_PRED + 32*64*300*50

// ---- K0: build M in MFMA-fragment order.
// Logical M[640][320]: rows 0..255 = C, 256..555 = A, rest 0; cols k<300 real, else 0.
// dst elem = ((mt*10 + ks)*64 + lane)*8 + e, m = mt*16 + (lane&15), k = ks*32 + (lane>>4)*8 + e.
__global__ void build_M(const float* __restrict__ A, const float* __restrict__ C,
                        _Float16* __restrict__ M) {
    int idx = blockIdx.x * 256 + threadIdx.x;
    if (idx >= 640 * 320) return;
    int e    = idx & 7;
    int lane = (idx >> 3) & 63;
    int fs   = idx >> 9;                        // mt*10 + ks
    int mt = fs / 10, ks = fs % 10;
    int m = mt * 16 + (lane & 15);
    int k = ks * 32 + (lane >> 4) * 8 + e;
    float v = 0.f;
    if (k < 300) {
        if (m < 256) v = C[m * 300 + k];
        else if (m < 556) v = A[(m - 256) * 300 + k];
    }
    M[idx] = (_Float16)v;
}

// ---- K1: block (bp, mhalf) — R10 structure + chunked XCD swizzle + merged stage phase.
//      256 thr / 4 waves: wave g owns m-rows [80g,80g+80) of the half (5 mt) x 4 n-tiles.
//      acc = 5x4 = 80 AGPR. launch_bounds(256,3) -> 3 blocks/CU.
//      LDS: 64 rows x 320 fp16, stride 640 B, swz: byte ^ ((row&7)<<4).
//      XCD swizzle: hw block b -> orig = (b&7)*512 + (b>>3); each XCD gets a contiguous
//      512-block chunk -> M-half L2-pinned per XCD, bp's two blocks adjacent on one XCD.
__global__ __launch_bounds__(256, 3) void gemm_main(
    const float* __restrict__ X, const float* __restrict__ x0,
    const _Float16* __restrict__ M, float* __restrict__ out)
{
    __shared__ _Float16 lds[64 * 320];   // 40960 B
    char* ldsb = (char*)lds;
    const int orig = ((blockIdx.x & 7) << 9) + (blockIdx.x >> 3);   // 4096 = 8*512, bijective
    const int bp = orig >> 1, mhalf = orig & 1;
    const int b = bp >> 6, p = bp & 63;
    const int tid = threadIdx.x;
    const float* Xbp = X + bp * 15000;

    const int wave = tid >> 6, lane = tid & 63;
    const int lr = lane & 15, lg = lane >> 4;
    const int g = wave;

    // ---- single staging phase: pad-zero + x0 + X, disjoint bytes, ONE barrier ----
    // (a) pad cols [600,640) of rows 0..50 (swizzled, 8B chunks)
    if (tid < 255) {
        int row = tid / 5, c = tid % 5;
        *(ull*)(ldsb + row * 640 + ((600 + c * 8) ^ ((row & 7) << 4))) = 0ULL;
    }
    // (b) rows 51..63 fully zero — XOR swizzle permutes within a row, so linear is fine
    #pragma unroll
    for (int u = 0; u < 5; u++) {
        int i = tid + u * 256;
        if (i < 1040) *(ull*)(ldsb + 51 * 640 + i * 8) = 0ULL;
    }
    // (c) x0 -> row 0 (row 0 swizzle = identity)
    if (tid < 75) {
        f32x4 v = *(const f32x4*)(x0 + bp * 300 + tid * 4);
        half4v h4 = { (_Float16)v.x, (_Float16)v.y, (_Float16)v.z, (_Float16)v.w };
        *(half4v*)(ldsb + tid * 8) = h4;
    }
    // (d) X (k-major [300][50]) -> rows n=t+1 (transposed), 8B swizzled writes
    for (int i = tid; i < 3750; i += 256) {
        int t = i % 50, jq = i / 50;
        const float* s = Xbp + (jq * 4) * 50 + t;
        half4v h4 = { (_Float16)s[0], (_Float16)s[50], (_Float16)s[100], (_Float16)s[150] };
        int row = t + 1;
        *(half4v*)(ldsb + row * 640 + ((jq * 8) ^ ((row & 7) << 4))) = h4;
    }
    __syncthreads();

    f32x4 acc[5][4];
    #pragma unroll
    for (int j = 0; j < 5; j++)
        #pragma unroll
        for (int nt = 0; nt < 4; nt++)
            acc[j][nt] = (f32x4){0.f, 0.f, 0.f, 0.f};

    // B-frag (fragment-ordered M): global m-group = mhalf*4 + g, frag (mt,ks) = 1KB burst
    const _Float16* Mw = M + (mhalf * 4 + g) * 50 * 512 + lane * 8;
    // A-frag: row = nt*16 + lr
    #define LDSA(nt, ks) (*(const half8*)(ldsb + ((nt) * 16 + lr) * 640 + \
                         (((ks) * 64 + lg * 16) ^ ((lr & 7) << 4))))

    #pragma unroll
    for (int ks = 0; ks < 10; ks++) {
        half8 bf0 = *(const half8*)(Mw + (0 * 10 + ks) * 512);
        half8 bf1 = *(const half8*)(Mw + (1 * 10 + ks) * 512);
        half8 bf2 = *(const half8*)(Mw + (2 * 10 + ks) * 512);
        half8 bf3 = *(const half8*)(Mw + (3 * 10 + ks) * 512);
        half8 bf4 = *(const half8*)(Mw + (4 * 10 + ks) * 512);
        #pragma unroll
        for (int nt = 0; nt < 4; nt++) {
            half8 a = LDSA(nt, ks);
            acc[0][nt] = __builtin_amdgcn_mfma_f32_16x16x32_f16(a, bf0, acc[0][nt], 0, 0, 0);
            acc[1][nt] = __builtin_amdgcn_mfma_f32_16x16x32_f16(a, bf1, acc[1][nt], 0, 0, 0);
            acc[2][nt] = __builtin_amdgcn_mfma_f32_16x16x32_f16(a, bf2, acc[2][nt], 0, 0, 0);
            acc[3][nt] = __builtin_amdgcn_mfma_f32_16x16x32_f16(a, bf3, acc[3][nt], 0, 0, 0);
            acc[4][nt] = __builtin_amdgcn_mfma_f32_16x16x32_f16(a, bf4, acc[4][nt], 0, 0, 0);
        }
    }

    // epilogue: col m = mhalf*320 + g*80 + j*16 + lr, ext-col n = nt*16 + lg*4 + q
    const int gr = p >> 3, gc = p & 7;
    #pragma unroll
    for (int j = 0; j < 5; j++) {
        int colm = mhalf * 320 + g * 80 + j * 16 + lr;
        if (colm < 256) {
            // recon row d = colm -> vid[b][gr*16 + d/16][gc*16 + d%16][t], t = n-1
            int base = b * 819200 + ((gr * 16 + (colm >> 4)) * 128 + gc * 16 + (colm & 15)) * 50;
            #pragma unroll
            for (int nt = 0; nt < 4; nt++) {
                int t0 = nt * 16 + lg * 4;
                if (t0 == 0) {
                    out[base + 0] = acc[j][0][1];
                    out[base + 1] = acc[j][0][2];
                    out[base + 2] = acc[j][0][3];
                } else if (t0 <= 46) {
                    f32x4 v = acc[j][nt];
                    __builtin_memcpy(&out[base + t0 - 1], &v, 16);
                } else if (t0 == 48) {
                    out[base + 47] = acc[j][nt][0];
                    out[base + 48] = acc[j][nt][1];
                    out[base + 49] = acc[j][nt][2];
                }
            }
        } else if (colm < 556) {
            // X_pred row i = colm-256, t = n
            int base = OFF_PRED + (bp * 300 + (colm - 256)) * 50;
            #pragma unroll
            for (int nt = 0; nt < 4; nt++) {
                int t0 = nt * 16 + lg * 4;
                if (t0 <= 46) {
                    f32x4 v = acc[j][nt];
                    __builtin_memcpy(&out[base + t0], &v, 16);
                } else if (t0 == 48) {
                    out[base + 48] = acc[j][nt][0];
                    out[base + 49] = acc[j][nt][1];
                }
            }
        }
    }
    #undef LDSA
}

// ---- K2: X_U[b,i,t] = 0.5*(1+exp(-(B·U)[b,i,t])) * sum_p |X[b,p,i,t]|
__global__ void xu_kernel(const float* __restrict__ X, const float* __restrict__ U,
                          const float* __restrict__ B, float* __restrict__ out) {
    int id = blockIdx.x * 256 + threadIdx.x;
    if (id >= 480000) return;
    int t = id % 50;
    int i = (id / 50) % 300;
    int b = id / 15000;
    const float* xp = X + b * 960000 + i * 50 + t;
    float s = 0.f;
    #pragma unroll 8
    for (int pp = 0; pp < 64; pp++) s += fabsf(xp[pp * 15000]);
    float bu = 0.f;
    const float* up = U + b * 2000 + t;
    const float* Bp = B + i * 40;
    #pragma unroll 8
    for (int q = 0; q < 40; q++) bu += Bp[q] * up[q * 50];
    out[OFF_XU + id] = 0.5f * (1.f + expf(-bu)) * s;
}

extern "C" void kernel_launch(void* const* d_in, const int* in_sizes, int n_in,
                              void* d_out, int out_size, void* d_ws, size_t ws_size,
                              hipStream_t stream) {
    const float* X  = (const float*)d_in[0];
    const float* U  = (const float*)d_in[1];
    const float* x0 = (const float*)d_in[2];
    const float* A  = (const float*)d_in[3];
    const float* B  = (const float*)d_in[4];
    const float* C  = (const float*)d_in[5];
    float* out = (float*)d_out;
    _Float16* M = (_Float16*)d_ws;      // 640*320*2 = 409,600 B (fragment-ordered)

    build_M<<<800, 256, 0, stream>>>(A, C, M);
    gemm_main<<<4096, 256, 0, stream>>>(X, x0, M, out);
    xu_kernel<<<1875, 256, 0, stream>>>(X, U, B, out);
}